// Round 1
// baseline (23412.917 us; speedup 1.0000x reference)
//
#include <hip/hip_runtime.h>
#include <float.h>
#include <math.h>

#define B_    128
#define H_    512
#define V_    1000
#define T_    256
#define G4_   2048
#define NBLK  256

// ---------------------------------------------------------------------------
// Precompute GEMM:  C[M][N] = A[M][0:512] * Bm[N][koff:koff+512]^T (+bias1+bias2)
// K fixed = 512. grid = (N/64, ceil(M/64)), block = 256.
// ---------------------------------------------------------------------------
__global__ __launch_bounds__(256) void gemm_nt_k512(
    const float* __restrict__ A, int M,
    const float* __restrict__ Bm, int ldb, int koff,
    const float* __restrict__ bias1, const float* __restrict__ bias2,
    float* __restrict__ C, int ldc)
{
  __shared__ float As[16][68];
  __shared__ float Bs[16][68];
  const int tid = threadIdx.x;
  const int m0 = blockIdx.y * 64, n0 = blockIdx.x * 64;
  const int tm = tid & 15, tn = tid >> 4;
  const int lm = tid & 63, kq = tid >> 6;
  float acc[4][4] = {};
  for (int k0 = 0; k0 < 512; k0 += 16) {
    float4 av = make_float4(0.f, 0.f, 0.f, 0.f);
    if (m0 + lm < M) av = *(const float4*)(A + (size_t)(m0 + lm) * 512 + k0 + kq * 4);
    float4 bv = *(const float4*)(Bm + (size_t)(n0 + lm) * ldb + koff + k0 + kq * 4);
    __syncthreads();
    As[kq*4+0][lm] = av.x; As[kq*4+1][lm] = av.y; As[kq*4+2][lm] = av.z; As[kq*4+3][lm] = av.w;
    Bs[kq*4+0][lm] = bv.x; Bs[kq*4+1][lm] = bv.y; Bs[kq*4+2][lm] = bv.z; Bs[kq*4+3][lm] = bv.w;
    __syncthreads();
#pragma unroll
    for (int kk = 0; kk < 16; ++kk) {
      const float4 a = *(const float4*)&As[kk][tm * 4];
      const float4 b = *(const float4*)&Bs[kk][tn * 4];
      const float aa[4] = {a.x, a.y, a.z, a.w};
      const float bb[4] = {b.x, b.y, b.z, b.w};
#pragma unroll
      for (int i = 0; i < 4; ++i)
#pragma unroll
        for (int j = 0; j < 4; ++j)
          acc[i][j] = fmaf(aa[i], bb[j], acc[i][j]);
    }
  }
#pragma unroll
  for (int i = 0; i < 4; ++i) {
    const int m = m0 + tm * 4 + i;
    if (m < M) {
#pragma unroll
      for (int j = 0; j < 4; ++j) {
        const int n = n0 + tn * 4 + j;
        float v = acc[i][j];
        if (bias1) v += bias1[n];
        if (bias2) v += bias2[n];
        C[(size_t)m * ldc + n] = v;
      }
    }
  }
}

// ---------------------------------------------------------------------------
// Init: h0 = context, argmax partials seeded so first combine yields start_id,
// barrier counters zeroed.  grid = 64 x 256.
// ---------------------------------------------------------------------------
__global__ __launch_bounds__(256) void init_kernel(
    const float* __restrict__ ctx, float* __restrict__ hbuf,
    float* __restrict__ argval, int* __restrict__ argidx,
    int* __restrict__ bar, const int* __restrict__ start_id)
{
  const int i = blockIdx.x * blockDim.x + threadIdx.x;
  if (i < B_ * H_ / 4) ((float4*)hbuf)[i] = ((const float4*)ctx)[i];
  if (i < B_ * 16) {
    const int j = i & 15;
    argval[i] = (j == 0) ? FLT_MAX : -FLT_MAX;
    argidx[i] = (j == 0) ? *start_id : 0;
  }
  if (i == 0) { bar[0] = 0; bar[1] = 0; }
}

// ---------------------------------------------------------------------------
// Device-scope grid barrier (cooperative launch guarantees co-residency).
// bar[0] = count, bar[1] = generation.
// ---------------------------------------------------------------------------
__device__ __forceinline__ void grid_barrier(int* bar)
{
  __syncthreads();
  if (threadIdx.x == 0) {
    __threadfence();  // agent-scope release of all prior writes
    const int g = __hip_atomic_load(bar + 1, __ATOMIC_RELAXED, __HIP_MEMORY_SCOPE_AGENT);
    const int v = __hip_atomic_fetch_add(bar, 1, __ATOMIC_ACQ_REL, __HIP_MEMORY_SCOPE_AGENT);
    if (v == NBLK - 1) {
      __hip_atomic_store(bar, 0, __ATOMIC_RELAXED, __HIP_MEMORY_SCOPE_AGENT);
      __hip_atomic_fetch_add(bar + 1, 1, __ATOMIC_RELEASE, __HIP_MEMORY_SCOPE_AGENT);
    } else {
      while (__hip_atomic_load(bar + 1, __ATOMIC_ACQUIRE, __HIP_MEMORY_SCOPE_AGENT) == g) {
        __builtin_amdgcn_s_sleep(2);
      }
    }
    __threadfence();  // agent-scope acquire for subsequent plain loads
  }
  __syncthreads();
}

// ---------------------------------------------------------------------------
// Persistent cooperative decoder.
// Phase 1 (per step): gates tile 16 rows x 16 hidden units (64 gate rows),
//   K split across 4 waves, LDS combine, LSTM epilogue (c in registers).
// Phase 2: logits tile 8 rows x 64 vocab + bias + argmax partials.
// ---------------------------------------------------------------------------
__global__ __launch_bounds__(256) void decoder_main(
    const float* __restrict__ Whh,
    const float* __restrict__ Wout,
    const float* __restrict__ bout,
    const float* __restrict__ proj,
    const float* __restrict__ basep,
    float* __restrict__ hbuf,
    float* __restrict__ argval,
    int* __restrict__ argidx,
    int* __restrict__ bar,
    float* __restrict__ out)
{
  __shared__ union SM {
    struct {
      float hs[16][516];    // h tile, padded stride (2-way bank alias only)
      float pbuf[4][1024];  // per-wave partials: slot = gl*16 + rl
      float gbuf[16][68];   // gates for LSTM: [rl][ul*4+gi]
      int   tok[16];
    } p1;
    struct {
      float hs[8][516];
      float pbuf[4][512];   // slot = vl*8 + rl
      float lbuf[8][64];
    } p2;
  } sm;

  const int tid  = threadIdx.x;
  const int bid  = blockIdx.x;
  // XCD-friendly swizzle: bid%8 = XCD -> weight slices stay L2-resident
  const int hg   = bid & 31;   // phase1: hidden group (16 units)
  const int rg   = bid >> 5;   // phase1: row group (16 rows)
  const int vg   = bid & 15;   // phase2: vocab tile (64)
  const int rg2  = bid >> 4;   // phase2: row group (8 rows)
  const int kc   = tid >> 6;   // wave id = K-chunk (128)
  const int lane = tid & 63;
  const int gq   = lane & 15;  // gate-quad / vocab-quad
  const int rq   = lane >> 4;  // row-quad

  float c_reg = 0.f;           // cell state for (row rg*16 + tid>>4, unit hg*16 + tid&15)

  const size_t BTVo = (size_t)B_ * T_ * V_;

  for (int t = 0; t < T_; ++t) {
    const int ping = t & 1;
    const float* hsrc = hbuf + (size_t)ping * (B_ * H_);
    float* hdst = hbuf + (size_t)(1 - ping) * (B_ * H_);

    // ---------------- Phase 1: gates + LSTM ----------------
    // stage h tile (16 rows x 512) + combine argmax partials -> tok
#pragma unroll
    for (int i = 0; i < 8; ++i) {
      const int idx = tid + i * 256;          // float4 index, 2048 total
      const int r = idx >> 7, k4 = idx & 127;
      *(float4*)&sm.p1.hs[r][k4 * 4] =
          *(const float4*)(hsrc + (size_t)(rg * 16 + r) * H_ + k4 * 4);
    }
    if (tid < 16) {
      const int row = rg * 16 + tid;
      float bv = argval[row * 16 + 0];
      int   bi = argidx[row * 16 + 0];
#pragma unroll
      for (int j = 1; j < 16; ++j) {
        const float v = argval[row * 16 + j];
        if (v > bv) { bv = v; bi = argidx[row * 16 + j]; }
      }
      sm.p1.tok[tid] = bi;
    }
    __syncthreads();

    {
      float acc[4][4];
#pragma unroll
      for (int a = 0; a < 4; ++a)
#pragma unroll
        for (int b = 0; b < 4; ++b) acc[a][b] = 0.f;

      const int kbase = kc * 128;
      const int u = hg * 16 + gq;
      const float* wp0 = Whh + (size_t)(u +    0) * H_ + kbase;
      const float* wp1 = Whh + (size_t)(u +  512) * H_ + kbase;
      const float* wp2 = Whh + (size_t)(u + 1024) * H_ + kbase;
      const float* wp3 = Whh + (size_t)(u + 1536) * H_ + kbase;
#pragma unroll 2
      for (int kk = 0; kk < 128; kk += 4) {
        const float4 w0 = *(const float4*)(wp0 + kk);
        const float4 w1 = *(const float4*)(wp1 + kk);
        const float4 w2 = *(const float4*)(wp2 + kk);
        const float4 w3 = *(const float4*)(wp3 + kk);
#pragma unroll
        for (int ri = 0; ri < 4; ++ri) {
          const float4 h4 = *(const float4*)&sm.p1.hs[rq * 4 + ri][kbase + kk];
          acc[0][ri] = fmaf(w0.x, h4.x, fmaf(w0.y, h4.y, fmaf(w0.z, h4.z, fmaf(w0.w, h4.w, acc[0][ri]))));
          acc[1][ri] = fmaf(w1.x, h4.x, fmaf(w1.y, h4.y, fmaf(w1.z, h4.z, fmaf(w1.w, h4.w, acc[1][ri]))));
          acc[2][ri] = fmaf(w2.x, h4.x, fmaf(w2.y, h4.y, fmaf(w2.z, h4.z, fmaf(w2.w, h4.w, acc[2][ri]))));
          acc[3][ri] = fmaf(w3.x, h4.x, fmaf(w3.y, h4.y, fmaf(w3.z, h4.z, fmaf(w3.w, h4.w, acc[3][ri]))));
        }
      }
#pragma unroll
      for (int gi = 0; gi < 4; ++gi) {
        *(float4*)&sm.p1.pbuf[kc][(gq * 4 + gi) * 16 + rq * 4] =
            make_float4(acc[gi][0], acc[gi][1], acc[gi][2], acc[gi][3]);
      }
    }
    __syncthreads();

    // combine K-partials + base + proj-emb -> gbuf
    {
      const int gl = tid >> 2;
      const int r0 = (tid & 3) * 4;
      const int s  = gl * 16 + r0;
      const float4 v0 = *(const float4*)&sm.p1.pbuf[0][s];
      const float4 v1 = *(const float4*)&sm.p1.pbuf[1][s];
      const float4 v2 = *(const float4*)&sm.p1.pbuf[2][s];
      const float4 v3 = *(const float4*)&sm.p1.pbuf[3][s];
      const float sum[4] = {v0.x + v1.x + v2.x + v3.x, v0.y + v1.y + v2.y + v3.y,
                            v0.z + v1.z + v2.z + v3.z, v0.w + v1.w + v2.w + v3.w};
      const int ul = gl >> 2, gi = gl & 3;
      const int gidx = hg * 16 + ul + gi * 512;
#pragma unroll
      for (int j = 0; j < 4; ++j) {
        const int row = rg * 16 + r0 + j;
        const int tk  = sm.p1.tok[r0 + j];
        sm.p1.gbuf[r0 + j][ul * 4 + gi] =
            sum[j] + basep[(size_t)row * G4_ + gidx] + proj[(size_t)tk * G4_ + gidx];
      }
    }
    __syncthreads();

    // LSTM epilogue: thread owns fixed (row, unit); c stays in register
    {
      const int rl = tid >> 4, ul = tid & 15;
      const float4 g4 = *(const float4*)&sm.p1.gbuf[rl][ul * 4];
      const float ig = 1.f / (1.f + expf(-g4.x));
      const float fg = 1.f / (1.f + expf(-g4.y));
      const float gg = tanhf(g4.z);
      const float og = 1.f / (1.f + expf(-g4.w));
      const float cn = fg * c_reg + ig * gg;
      c_reg = cn;
      const float hn = og * tanhf(cn);
      const int row = rg * 16 + rl, hid = hg * 16 + ul;
      hdst[(size_t)row * H_ + hid] = hn;
      if (t == T_ - 1) {
        out[BTVo + (size_t)row * H_ + hid] = hn;                    // h_f
        out[BTVo + (size_t)B_ * H_ + (size_t)row * H_ + hid] = cn;  // c_f
      }
    }
    grid_barrier(bar);   // barrier A: h_new visible grid-wide

    // ---------------- Phase 2: logits + argmax ----------------
#pragma unroll
    for (int i = 0; i < 4; ++i) {
      const int idx = tid + i * 256;          // 1024 float4
      const int r = idx >> 7, k4 = idx & 127;
      *(float4*)&sm.p2.hs[r][k4 * 4] =
          *(const float4*)(hdst + (size_t)(rg2 * 8 + r) * H_ + k4 * 4);
    }
    __syncthreads();

    {
      float acc2[4][2];
#pragma unroll
      for (int a = 0; a < 4; ++a) { acc2[a][0] = 0.f; acc2[a][1] = 0.f; }
      const int kbase = kc * 128;
      const float* wq[4];
#pragma unroll
      for (int vi = 0; vi < 4; ++vi) {
        const int v = vg * 64 + gq * 4 + vi;
        wq[vi] = Wout + (size_t)(v < V_ ? v : 0) * H_ + kbase;
      }
#pragma unroll 2
      for (int kk = 0; kk < 128; kk += 4) {
        const float4 w0 = *(const float4*)(wq[0] + kk);
        const float4 w1 = *(const float4*)(wq[1] + kk);
        const float4 w2 = *(const float4*)(wq[2] + kk);
        const float4 w3 = *(const float4*)(wq[3] + kk);
#pragma unroll
        for (int ri = 0; ri < 2; ++ri) {
          const float4 h4 = *(const float4*)&sm.p2.hs[rq * 2 + ri][kbase + kk];
          acc2[0][ri] = fmaf(w0.x, h4.x, fmaf(w0.y, h4.y, fmaf(w0.z, h4.z, fmaf(w0.w, h4.w, acc2[0][ri]))));
          acc2[1][ri] = fmaf(w1.x, h4.x, fmaf(w1.y, h4.y, fmaf(w1.z, h4.z, fmaf(w1.w, h4.w, acc2[1][ri]))));
          acc2[2][ri] = fmaf(w2.x, h4.x, fmaf(w2.y, h4.y, fmaf(w2.z, h4.z, fmaf(w2.w, h4.w, acc2[2][ri]))));
          acc2[3][ri] = fmaf(w3.x, h4.x, fmaf(w3.y, h4.y, fmaf(w3.z, h4.z, fmaf(w3.w, h4.w, acc2[3][ri]))));
        }
      }
#pragma unroll
      for (int vi = 0; vi < 4; ++vi) {
        sm.p2.pbuf[kc][(gq * 4 + vi) * 8 + rq * 2 + 0] = acc2[vi][0];
        sm.p2.pbuf[kc][(gq * 4 + vi) * 8 + rq * 2 + 1] = acc2[vi][1];
      }
    }
    __syncthreads();

    // combine + bias + store logits + lbuf
    {
      const int vl = tid >> 2;
      const int r0 = (tid & 3) * 2;
      const int s  = vl * 8 + r0;
      float s0 = sm.p2.pbuf[0][s] + sm.p2.pbuf[1][s] + sm.p2.pbuf[2][s] + sm.p2.pbuf[3][s];
      float s1 = sm.p2.pbuf[0][s+1] + sm.p2.pbuf[1][s+1] + sm.p2.pbuf[2][s+1] + sm.p2.pbuf[3][s+1];
      const int v = vg * 64 + vl;
      if (v < V_) {
        const float bz = bout[v];
        s0 += bz; s1 += bz;
        const int row0 = rg2 * 8 + r0;
        out[((size_t)row0 * T_ + t) * V_ + v] = s0;
        out[((size_t)(row0 + 1) * T_ + t) * V_ + v] = s1;
        sm.p2.lbuf[r0][vl] = s0;
        sm.p2.lbuf[r0 + 1][vl] = s1;
      } else {
        sm.p2.lbuf[r0][vl] = -FLT_MAX;
        sm.p2.lbuf[r0 + 1][vl] = -FLT_MAX;
      }
    }
    __syncthreads();

    // per-tile argmax partial (first-index tie-break: ascending scan, strict >)
    if (tid < 8) {
      float bv = sm.p2.lbuf[tid][0];
      int bi = 0;
      for (int j = 1; j < 64; ++j) {
        const float v = sm.p2.lbuf[tid][j];
        if (v > bv) { bv = v; bi = j; }
      }
      const int row = rg2 * 8 + tid;
      argval[row * 16 + vg] = bv;
      argidx[row * 16 + vg] = vg * 64 + bi;
    }
    grid_barrier(bar);   // barrier B: argmax partials visible
  }
}

// ---------------------------------------------------------------------------
extern "C" void kernel_launch(void* const* d_in, const int* in_sizes, int n_in,
                              void* d_out, int out_size, void* d_ws, size_t ws_size,
                              hipStream_t stream)
{
  const float* ctx   = (const float*)d_in[0];
  const float* emb   = (const float*)d_in[1];
  const float* Wih   = (const float*)d_in[2];
  const float* bih   = (const float*)d_in[3];
  const float* Whh   = (const float*)d_in[4];
  const float* bhh   = (const float*)d_in[5];
  const float* Wout  = (const float*)d_in[6];
  const float* bout  = (const float*)d_in[7];
  const int*   start = (const int*)d_in[8];
  float* out = (float*)d_out;

  // workspace layout (floats)
  float* wsf    = (float*)d_ws;
  float* proj   = wsf;                       // 1000*2048 = 2,048,000
  float* basep  = wsf + 2048000;             // 128*2048  =   262,144
  float* hbuf   = wsf + 2310144;             // 2*128*512 =   131,072
  float* argval = wsf + 2441216;             // 128*16    =     2,048
  int*   argidx = (int*)(wsf + 2443264);     // 128*16
  int*   bar    = (int*)(wsf + 2445312);     // 2 ints

  // base = context @ W_ih[:, :512]^T + b_ih + b_hh
  hipLaunchKernelGGL(gemm_nt_k512, dim3(32, 2), dim3(256), 0, stream,
                     ctx, B_, Wih, 1024, 0, bih, bhh, basep, G4_);
  // proj = embed_table @ W_ih[:, 512:]^T
  hipLaunchKernelGGL(gemm_nt_k512, dim3(32, 16), dim3(256), 0, stream,
                     emb, V_, Wih, 1024, 512, (const float*)nullptr, (const float*)nullptr,
                     proj, G4_);
  hipLaunchKernelGGL(init_kernel, dim3(64), dim3(256), 0, stream,
                     ctx, hbuf, argval, argidx, bar, start);

  void* args[] = {(void*)&Whh, (void*)&Wout, (void*)&bout, (void*)&proj, (void*)&basep,
                  (void*)&hbuf, (void*)&argval, (void*)&argidx, (void*)&bar, (void*)&out};
  hipLaunchCooperativeKernel(reinterpret_cast<const void*>(decoder_main),
                             dim3(NBLK), dim3(256), args, 0, stream);
}

// Round 2
// 9679.914 us; speedup vs baseline: 2.4187x; 2.4187x over previous
//
#include <hip/hip_runtime.h>
#include <float.h>
#include <math.h>

#define B_    128
#define H_    512
#define V_    1000
#define T_    256
#define G4_   2048
#define NBLK  256

#define AT_LOAD(p)    __hip_atomic_load((p), __ATOMIC_RELAXED, __HIP_MEMORY_SCOPE_AGENT)
#define AT_STORE(p,v) __hip_atomic_store((p), (v), __ATOMIC_RELAXED, __HIP_MEMORY_SCOPE_AGENT)

// ---------------------------------------------------------------------------
// Precompute GEMM:  C[M][N] = A[M][0:512] * Bm[N][koff:koff+512]^T (+bias1+bias2)
// ---------------------------------------------------------------------------
__global__ __launch_bounds__(256) void gemm_nt_k512(
    const float* __restrict__ A, int M,
    const float* __restrict__ Bm, int ldb, int koff,
    const float* __restrict__ bias1, const float* __restrict__ bias2,
    float* __restrict__ C, int ldc)
{
  __shared__ float As[16][68];
  __shared__ float Bs[16][68];
  const int tid = threadIdx.x;
  const int m0 = blockIdx.y * 64, n0 = blockIdx.x * 64;
  const int tm = tid & 15, tn = tid >> 4;
  const int lm = tid & 63, kq = tid >> 6;
  float acc[4][4] = {};
  for (int k0 = 0; k0 < 512; k0 += 16) {
    float4 av = make_float4(0.f, 0.f, 0.f, 0.f);
    if (m0 + lm < M) av = *(const float4*)(A + (size_t)(m0 + lm) * 512 + k0 + kq * 4);
    float4 bv = *(const float4*)(Bm + (size_t)(n0 + lm) * ldb + koff + k0 + kq * 4);
    __syncthreads();
    As[kq*4+0][lm] = av.x; As[kq*4+1][lm] = av.y; As[kq*4+2][lm] = av.z; As[kq*4+3][lm] = av.w;
    Bs[kq*4+0][lm] = bv.x; Bs[kq*4+1][lm] = bv.y; Bs[kq*4+2][lm] = bv.z; Bs[kq*4+3][lm] = bv.w;
    __syncthreads();
#pragma unroll
    for (int kk = 0; kk < 16; ++kk) {
      const float4 a = *(const float4*)&As[kk][tm * 4];
      const float4 b = *(const float4*)&Bs[kk][tn * 4];
      const float aa[4] = {a.x, a.y, a.z, a.w};
      const float bb[4] = {b.x, b.y, b.z, b.w};
#pragma unroll
      for (int i = 0; i < 4; ++i)
#pragma unroll
        for (int j = 0; j < 4; ++j)
          acc[i][j] = fmaf(aa[i], bb[j], acc[i][j]);
    }
  }
#pragma unroll
  for (int i = 0; i < 4; ++i) {
    const int m = m0 + tm * 4 + i;
    if (m < M) {
#pragma unroll
      for (int j = 0; j < 4; ++j) {
        const int n = n0 + tn * 4 + j;
        float v = acc[i][j];
        if (bias1) v += bias1[n];
        if (bias2) v += bias2[n];
        C[(size_t)m * ldc + n] = v;
      }
    }
  }
}

// ---------------------------------------------------------------------------
__global__ __launch_bounds__(256) void init_kernel(
    const float* __restrict__ ctx, float* __restrict__ hbuf,
    float* __restrict__ argval, int* __restrict__ argidx,
    int* __restrict__ flags, int* __restrict__ go,
    const int* __restrict__ start_id)
{
  const int i = blockIdx.x * blockDim.x + threadIdx.x;
  if (i < B_ * H_ / 4) ((float4*)hbuf)[i] = ((const float4*)ctx)[i];
  if (i < B_ * 16) {
    const int j = i & 15;
    argval[i] = (j == 0) ? FLT_MAX : -FLT_MAX;
    argidx[i] = (j == 0) ? *start_id : 0;
  }
  if (i < 256) flags[i] = 0;
  if (i < 128) go[i] = 0;
}

// ---------------------------------------------------------------------------
// Group barrier over 32 blocks (bids [32g,32g+32)) — no RMW, no cache fences.
// Release order is guaranteed by the compiler's full s_waitcnt before
// s_barrier (__syncthreads drains vmcnt = acks of agent-scope stores);
// cross-block data travels exclusively via sc0/sc1-bypass atomics, so no
// L2 writeback/invalidate is ever needed and weights stay cached.
// ---------------------------------------------------------------------------
__device__ __forceinline__ void group_barrier(int* flags, int* go,
                                              int gid, int mem, int gen)
{
  __syncthreads();                     // drains all waves' outstanding stores
  if (threadIdx.x == 0)
    AT_STORE(&flags[gid * 32 + mem], gen);
  if (mem == 0) {
    if (threadIdx.x < 64) {            // wave 0 gathers all 32 flags
      const int idx = gid * 32 + (threadIdx.x & 31);
      for (;;) {
        const int v = AT_LOAD(&flags[idx]);
        if (__all(v >= gen)) break;
        __builtin_amdgcn_s_sleep(1);
      }
      if (threadIdx.x == 0) AT_STORE(&go[gid * 16], gen);
    }
  } else {
    if (threadIdx.x == 0) {
      while (AT_LOAD(&go[gid * 16]) < gen) __builtin_amdgcn_s_sleep(1);
    }
  }
  __syncthreads();
}

// ---------------------------------------------------------------------------
// Persistent cooperative decoder. 8 independent groups of 32 blocks; each
// group owns 16 batch rows end-to-end.
// ---------------------------------------------------------------------------
__global__ __launch_bounds__(256) void decoder_main(
    const float* __restrict__ Whh,
    const float* __restrict__ Wout,
    const float* __restrict__ bout,
    const float* __restrict__ proj,
    const float* __restrict__ basep,
    float* __restrict__ hbuf,
    float* __restrict__ argval,
    int* __restrict__ argidx,
    int* __restrict__ flags,
    int* __restrict__ go,
    float* __restrict__ out)
{
  __shared__ union alignas(16) SM {
    struct {
      float hs[16][516];     // h tile (stride 516 -> only free 2-way aliasing)
      float pb1[4][64][20];  // K-partials [kc][gate-row][row*4..], padded
      float gbuf[16][68];    // gates [row][unit*4+gate]
      int   tok[16];
    } p1;
    struct {
      float hs[8][516];
      float pb2[4][64][12];  // [kc][vocab][row*2..], padded
      float lbuf[8][65];     // logit tile, padded
    } p2;
  } sm;

  const int tid  = threadIdx.x;
  const int bid  = blockIdx.x;
  const int gid  = bid >> 5;   // group (16 rows), 8 groups, fully independent
  const int mem  = bid & 31;   // member within group
  const int hg   = bid & 31;   // phase1: hidden group (16 units)
  const int rg   = bid >> 5;   // phase1: row group (16 rows)
  const int vg   = bid & 15;   // phase2: vocab tile (64)
  const int rg2  = bid >> 4;   // phase2: row group (8 rows)
  const int kc   = tid >> 6;   // wave id = K-chunk (128)
  const int lane = tid & 63;
  const int gq   = lane & 15;
  const int rq   = lane >> 4;

  float c_reg = 0.f;
  const size_t BTVo = (size_t)B_ * T_ * V_;

  for (int t = 0; t < T_; ++t) {
    const int ping = t & 1;
    const float* hsrc = hbuf + (size_t)ping * (B_ * H_);
    float* hdst = hbuf + (size_t)(1 - ping) * (B_ * H_);

    // ---------------- Phase 1: gates + LSTM ----------------
    {
      const unsigned long long* hq =
          (const unsigned long long*)(hsrc + (size_t)rg * 16 * H_);
#pragma unroll
      for (int i = 0; i < 16; ++i) {
        const int idx = tid + i * 256;       // 4096 x 8B
        const int r = idx >> 8, c = idx & 255;
        const unsigned long long v = AT_LOAD((unsigned long long*)&hq[(size_t)r * 256 + c]);
        *(unsigned long long*)&sm.p1.hs[r][c * 2] = v;
      }
    }
    {
      // parallel argmax combine: 16 rows x 16 partials, shuffle-reduce
      const int row = tid >> 4, j = tid & 15;
      float v = AT_LOAD(&argval[(rg * 16 + row) * 16 + j]);
      int  ix = AT_LOAD(&argidx[(rg * 16 + row) * 16 + j]);
#pragma unroll
      for (int d = 8; d >= 1; d >>= 1) {
        const float vo = __shfl_xor(v, d, 16);
        const int   io = __shfl_xor(ix, d, 16);
        if (vo > v || (vo == v && io < ix)) { v = vo; ix = io; }
      }
      if (j == 0) sm.p1.tok[row] = ix;
    }
    __syncthreads();

    {
      float acc[4][4];
#pragma unroll
      for (int a = 0; a < 4; ++a)
#pragma unroll
        for (int b = 0; b < 4; ++b) acc[a][b] = 0.f;

      const int kbase = kc * 128;
      const int u = hg * 16 + gq;
      const float* wp0 = Whh + (size_t)(u +    0) * H_ + kbase;
      const float* wp1 = Whh + (size_t)(u +  512) * H_ + kbase;
      const float* wp2 = Whh + (size_t)(u + 1024) * H_ + kbase;
      const float* wp3 = Whh + (size_t)(u + 1536) * H_ + kbase;
#pragma unroll 2
      for (int kk = 0; kk < 128; kk += 4) {
        const float4 w0 = *(const float4*)(wp0 + kk);
        const float4 w1 = *(const float4*)(wp1 + kk);
        const float4 w2 = *(const float4*)(wp2 + kk);
        const float4 w3 = *(const float4*)(wp3 + kk);
#pragma unroll
        for (int ri = 0; ri < 4; ++ri) {
          const float4 h4 = *(const float4*)&sm.p1.hs[rq * 4 + ri][kbase + kk];
          acc[0][ri] = fmaf(w0.x, h4.x, fmaf(w0.y, h4.y, fmaf(w0.z, h4.z, fmaf(w0.w, h4.w, acc[0][ri]))));
          acc[1][ri] = fmaf(w1.x, h4.x, fmaf(w1.y, h4.y, fmaf(w1.z, h4.z, fmaf(w1.w, h4.w, acc[1][ri]))));
          acc[2][ri] = fmaf(w2.x, h4.x, fmaf(w2.y, h4.y, fmaf(w2.z, h4.z, fmaf(w2.w, h4.w, acc[2][ri]))));
          acc[3][ri] = fmaf(w3.x, h4.x, fmaf(w3.y, h4.y, fmaf(w3.z, h4.z, fmaf(w3.w, h4.w, acc[3][ri]))));
        }
      }
#pragma unroll
      for (int gi = 0; gi < 4; ++gi)
        *(float4*)&sm.p1.pb1[kc][gq * 4 + gi][rq * 4] =
            make_float4(acc[gi][0], acc[gi][1], acc[gi][2], acc[gi][3]);
    }
    __syncthreads();

    // combine K-partials + base + proj-emb -> gbuf
    {
      const int gl = tid >> 2;
      const int r0 = (tid & 3) * 4;
      const float4 v0 = *(const float4*)&sm.p1.pb1[0][gl][r0];
      const float4 v1 = *(const float4*)&sm.p1.pb1[1][gl][r0];
      const float4 v2 = *(const float4*)&sm.p1.pb1[2][gl][r0];
      const float4 v3 = *(const float4*)&sm.p1.pb1[3][gl][r0];
      const float sum[4] = {v0.x + v1.x + v2.x + v3.x, v0.y + v1.y + v2.y + v3.y,
                            v0.z + v1.z + v2.z + v3.z, v0.w + v1.w + v2.w + v3.w};
      const int ul = gl >> 2, gi = gl & 3;
      const int gidx = hg * 16 + ul + gi * 512;
#pragma unroll
      for (int j = 0; j < 4; ++j) {
        const int row = rg * 16 + r0 + j;
        const int tk  = sm.p1.tok[r0 + j];
        sm.p1.gbuf[r0 + j][ul * 4 + gi] =
            sum[j] + basep[(size_t)row * G4_ + gidx] + proj[(size_t)tk * G4_ + gidx];
      }
    }
    __syncthreads();

    // LSTM epilogue: c stays in register; h broadcast via bypass atomics
    {
      const int rl = tid >> 4, ul = tid & 15;
      const float4 g4 = *(const float4*)&sm.p1.gbuf[rl][ul * 4];
      const float ig = 1.f / (1.f + expf(-g4.x));
      const float fg = 1.f / (1.f + expf(-g4.y));
      const float gg = tanhf(g4.z);
      const float og = 1.f / (1.f + expf(-g4.w));
      const float cn = fg * c_reg + ig * gg;
      c_reg = cn;
      const float hn = og * tanhf(cn);
      const int row = rg * 16 + rl, hid = hg * 16 + ul;
      AT_STORE(&hdst[(size_t)row * H_ + hid], hn);
      if (t == T_ - 1) {
        out[BTVo + (size_t)row * H_ + hid] = hn;                    // h_f
        out[BTVo + (size_t)B_ * H_ + (size_t)row * H_ + hid] = cn;  // c_f
      }
    }
    group_barrier(flags, go, gid, mem, 2 * t + 1);   // h visible in-group

    // ---------------- Phase 2: logits + argmax ----------------
    {
      const unsigned long long* hq2 =
          (const unsigned long long*)(hdst + (size_t)rg2 * 8 * H_);
#pragma unroll
      for (int i = 0; i < 8; ++i) {
        const int idx = tid + i * 256;       // 2048 x 8B
        const int r = idx >> 8, c = idx & 255;
        const unsigned long long v = AT_LOAD((unsigned long long*)&hq2[(size_t)r * 256 + c]);
        *(unsigned long long*)&sm.p2.hs[r][c * 2] = v;
      }
    }
    __syncthreads();

    {
      float acc2[4][2];
#pragma unroll
      for (int a = 0; a < 4; ++a) { acc2[a][0] = 0.f; acc2[a][1] = 0.f; }
      const int kbase = kc * 128;
      const float* wq[4];
#pragma unroll
      for (int vi = 0; vi < 4; ++vi) {
        const int v = vg * 64 + gq * 4 + vi;
        wq[vi] = Wout + (size_t)(v < V_ ? v : 0) * H_ + kbase;
      }
#pragma unroll 2
      for (int kk = 0; kk < 128; kk += 4) {
        const float4 w0 = *(const float4*)(wq[0] + kk);
        const float4 w1 = *(const float4*)(wq[1] + kk);
        const float4 w2 = *(const float4*)(wq[2] + kk);
        const float4 w3 = *(const float4*)(wq[3] + kk);
#pragma unroll
        for (int ri = 0; ri < 2; ++ri) {
          const float4 h4 = *(const float4*)&sm.p2.hs[rq * 2 + ri][kbase + kk];
          acc2[0][ri] = fmaf(w0.x, h4.x, fmaf(w0.y, h4.y, fmaf(w0.z, h4.z, fmaf(w0.w, h4.w, acc2[0][ri]))));
          acc2[1][ri] = fmaf(w1.x, h4.x, fmaf(w1.y, h4.y, fmaf(w1.z, h4.z, fmaf(w1.w, h4.w, acc2[1][ri]))));
          acc2[2][ri] = fmaf(w2.x, h4.x, fmaf(w2.y, h4.y, fmaf(w2.z, h4.z, fmaf(w2.w, h4.w, acc2[2][ri]))));
          acc2[3][ri] = fmaf(w3.x, h4.x, fmaf(w3.y, h4.y, fmaf(w3.z, h4.z, fmaf(w3.w, h4.w, acc2[3][ri]))));
        }
      }
#pragma unroll
      for (int vi = 0; vi < 4; ++vi)
        *(float2*)&sm.p2.pb2[kc][gq * 4 + vi][rq * 2] =
            make_float2(acc2[vi][0], acc2[vi][1]);
    }
    __syncthreads();

    // combine + bias + store logits + lbuf
    {
      const int vl = tid >> 2;
      const int r0 = (tid & 3) * 2;
      const float2 a0 = *(const float2*)&sm.p2.pb2[0][vl][r0];
      const float2 a1 = *(const float2*)&sm.p2.pb2[1][vl][r0];
      const float2 a2 = *(const float2*)&sm.p2.pb2[2][vl][r0];
      const float2 a3 = *(const float2*)&sm.p2.pb2[3][vl][r0];
      float s0 = a0.x + a1.x + a2.x + a3.x;
      float s1 = a0.y + a1.y + a2.y + a3.y;
      const int v = vg * 64 + vl;
      if (v < V_) {
        const float bz = bout[v];
        s0 += bz; s1 += bz;
        const int row0 = rg2 * 8 + r0;
        out[((size_t)row0 * T_ + t) * V_ + v] = s0;
        out[((size_t)(row0 + 1) * T_ + t) * V_ + v] = s1;
        sm.p2.lbuf[r0][vl] = s0;
        sm.p2.lbuf[r0 + 1][vl] = s1;
      } else {
        sm.p2.lbuf[r0][vl] = -FLT_MAX;
        sm.p2.lbuf[r0 + 1][vl] = -FLT_MAX;
      }
    }
    __syncthreads();

    // per-tile argmax partial: 8 rows x 64, shuffle-reduce width 32
    {
      const int r = tid >> 5, j = tid & 31;
      const float v1 = sm.p2.lbuf[r][j];
      const float v2 = sm.p2.lbuf[r][j + 32];
      float v; int ix;
      if (v2 > v1) { v = v2; ix = j + 32; } else { v = v1; ix = j; }
#pragma unroll
      for (int d = 16; d >= 1; d >>= 1) {
        const float vo = __shfl_xor(v, d, 32);
        const int   io = __shfl_xor(ix, d, 32);
        if (vo > v || (vo == v && io < ix)) { v = vo; ix = io; }
      }
      if (j == 0) {
        const int row = rg2 * 8 + r;
        AT_STORE(&argval[row * 16 + vg], v);
        AT_STORE(&argidx[row * 16 + vg], vg * 64 + ix);
      }
    }
    group_barrier(flags, go, gid, mem, 2 * t + 2);   // argmax partials visible
  }
}

// ---------------------------------------------------------------------------
extern "C" void kernel_launch(void* const* d_in, const int* in_sizes, int n_in,
                              void* d_out, int out_size, void* d_ws, size_t ws_size,
                              hipStream_t stream)
{
  const float* ctx   = (const float*)d_in[0];
  const float* emb   = (const float*)d_in[1];
  const float* Wih   = (const float*)d_in[2];
  const float* bih   = (const float*)d_in[3];
  const float* Whh   = (const float*)d_in[4];
  const float* bhh   = (const float*)d_in[5];
  const float* Wout  = (const float*)d_in[6];
  const float* bout  = (const float*)d_in[7];
  const int*   start = (const int*)d_in[8];
  float* out = (float*)d_out;

  // workspace layout (floats)
  float* wsf    = (float*)d_ws;
  float* proj   = wsf;                       // 1000*2048 = 2,048,000
  float* basep  = wsf + 2048000;             // 128*2048  =   262,144
  float* hbuf   = wsf + 2310144;             // 2*128*512 =   131,072
  float* argval = wsf + 2441216;             // 128*16    =     2,048
  int*   argidx = (int*)(wsf + 2443264);     // 128*16    =     2,048
  int*   flags  = (int*)(wsf + 2445312);     // 256
  int*   go     = (int*)(wsf + 2445568);     // 128

  hipLaunchKernelGGL(gemm_nt_k512, dim3(32, 2), dim3(256), 0, stream,
                     ctx, B_, Wih, 1024, 0, bih, bhh, basep, G4_);
  hipLaunchKernelGGL(gemm_nt_k512, dim3(32, 16), dim3(256), 0, stream,
                     emb, V_, Wih, 1024, 512, (const float*)nullptr, (const float*)nullptr,
                     proj, G4_);
  hipLaunchKernelGGL(init_kernel, dim3(64), dim3(256), 0, stream,
                     ctx, hbuf, argval, argidx, flags, go, start);

  void* args[] = {(void*)&Whh, (void*)&Wout, (void*)&bout, (void*)&proj, (void*)&basep,
                  (void*)&hbuf, (void*)&argval, (void*)&argidx, (void*)&flags, (void*)&go,
                  (void*)&out};
  hipLaunchCooperativeKernel(reinterpret_cast<const void*>(decoder_main),
                             dim3(NBLK), dim3(256), args, 0, stream);
}

// Round 5
// 9177.267 us; speedup vs baseline: 2.5512x; 1.0548x over previous
//
#include <hip/hip_runtime.h>
#include <float.h>
#include <math.h>

#define B_    128
#define H_    512
#define V_    1000
#define T_    256
#define G4_   2048
#define NBLK  256     // cooperative launch limit: 1 block/CU (512 failed to launch in r3/r4)

#define AT_LOAD(p)    __hip_atomic_load((p), __ATOMIC_RELAXED, __HIP_MEMORY_SCOPE_AGENT)
#define AT_STORE(p,v) __hip_atomic_store((p), (v), __ATOMIC_RELAXED, __HIP_MEMORY_SCOPE_AGENT)

// ---------------------------------------------------------------------------
// Precompute GEMM:  C[M][N] = A[M][0:512] * Bm[N][koff:koff+512]^T (+bias1+bias2)
// ---------------------------------------------------------------------------
__global__ __launch_bounds__(256) void gemm_nt_k512(
    const float* __restrict__ A, int M,
    const float* __restrict__ Bm, int ldb, int koff,
    const float* __restrict__ bias1, const float* __restrict__ bias2,
    float* __restrict__ C, int ldc)
{
  __shared__ float As[16][68];
  __shared__ float Bs[16][68];
  const int tid = threadIdx.x;
  const int m0 = blockIdx.y * 64, n0 = blockIdx.x * 64;
  const int tm = tid & 15, tn = tid >> 4;
  const int lm = tid & 63, kq = tid >> 6;
  float acc[4][4] = {};
  for (int k0 = 0; k0 < 512; k0 += 16) {
    float4 av = make_float4(0.f, 0.f, 0.f, 0.f);
    if (m0 + lm < M) av = *(const float4*)(A + (size_t)(m0 + lm) * 512 + k0 + kq * 4);
    float4 bv = *(const float4*)(Bm + (size_t)(n0 + lm) * ldb + koff + k0 + kq * 4);
    __syncthreads();
    As[kq*4+0][lm] = av.x; As[kq*4+1][lm] = av.y; As[kq*4+2][lm] = av.z; As[kq*4+3][lm] = av.w;
    Bs[kq*4+0][lm] = bv.x; Bs[kq*4+1][lm] = bv.y; Bs[kq*4+2][lm] = bv.z; Bs[kq*4+3][lm] = bv.w;
    __syncthreads();
#pragma unroll
    for (int kk = 0; kk < 16; ++kk) {
      const float4 a = *(const float4*)&As[kk][tm * 4];
      const float4 b = *(const float4*)&Bs[kk][tn * 4];
      const float aa[4] = {a.x, a.y, a.z, a.w};
      const float bb[4] = {b.x, b.y, b.z, b.w};
#pragma unroll
      for (int i = 0; i < 4; ++i)
#pragma unroll
        for (int j = 0; j < 4; ++j)
          acc[i][j] = fmaf(aa[i], bb[j], acc[i][j]);
    }
  }
#pragma unroll
  for (int i = 0; i < 4; ++i) {
    const int m = m0 + tm * 4 + i;
    if (m < M) {
#pragma unroll
      for (int j = 0; j < 4; ++j) {
        const int n = n0 + tn * 4 + j;
        float v = acc[i][j];
        if (bias1) v += bias1[n];
        if (bias2) v += bias2[n];
        C[(size_t)m * ldc + n] = v;
      }
    }
  }
}

// ---------------------------------------------------------------------------
// amax word: [val:f32 bits in high 32][tag:16][token:16]; tag(t) = t+2.
// ---------------------------------------------------------------------------
__global__ __launch_bounds__(256) void init_kernel(
    const float* __restrict__ ctx, float* __restrict__ hbuf,
    unsigned long long* __restrict__ amax,
    int* __restrict__ hdone, const int* __restrict__ start_id)
{
  const int i = blockIdx.x * blockDim.x + threadIdx.x;
  // h(-1) = context into slot 1
  ((float4*)(hbuf + B_ * H_))[i] = ((const float4*)ctx)[i];
  if (i < B_ * 32) {
    const int m = i & 31;
    const unsigned long long w = (m == 0)
        ? ((((unsigned long long)__float_as_uint(FLT_MAX)) << 32) |
           (1u << 16) | (unsigned)(*start_id))
        : ((((unsigned long long)__float_as_uint(-FLT_MAX)) << 32) | (1u << 16));
    amax[(size_t)B_ * 32 + i] = w;   // parity-1 slot, tag(-1)=1
  }
  if (i < 2 * 8 * 32) hdone[i * 16] = 0;
}

// ---------------------------------------------------------------------------
// Persistent cooperative decoder. 8 groups x 32 blocks; group g owns rows
// [16g,16g+16). ZERO group barriers: tagged-dataflow sync.
//   - tokens(t): amax[t&1][row][member], tagged t+2; phase1(t+1) polls tag t+1+... (expects (t)+2)
//   - h(t): untagged 8B pairs; freshness for phase2(t) via hdone[t&1][g][m]
//     flags (released by __syncthreads vmcnt drain — r2-verified mechanism);
//     freshness for phase1(t+1) is transitive through amax tags, and h(t) is
//     already resident in LDS from phase2(t) anyway (staging skipped).
// Slot reuse (distance 2) proven safe by transitive dependency chains.
// ---------------------------------------------------------------------------
__global__ __launch_bounds__(256) void decoder_main(
    const float* __restrict__ Whh,
    const float* __restrict__ Wout,
    const float* __restrict__ bout,
    const float* __restrict__ proj,
    const float* __restrict__ basep,
    float* __restrict__ hbuf,
    unsigned long long* __restrict__ amax,
    int* __restrict__ hdone,
    float* __restrict__ out)
{
  __shared__ struct alignas(16) SM {
    float hs[16][516];        // h tile, persists across phases (stride: 2-way alias only)
    union {
      struct {
        float pb1[4][64][20]; // K-partials [kc][gate-line][4*rq..]
        float gbuf[16][68];   // gates [row][unit*4+gate]
        int   tok[16];
      } p1;
      struct {
        float pb2[4][32][20]; // [kc][vocab-in-tile][row..]
        float lbuf[16][36];   // logit tile
      } p2;
    } u;
  } sm;

  const int tid  = threadIdx.x;
  const int bid  = blockIdx.x;
  const int gid  = bid >> 5;   // group: rows [16g, 16g+16)
  const int mem  = bid & 31;   // member: phase1 units [16*mem,+16); phase2 vocab [32*mem,+32)
  const int kc   = tid >> 6;   // wave id = K-chunk of 128
  const int lane = tid & 63;
  const int gq   = lane & 15;  // phase1 unit-in-slice
  const int rq   = lane >> 4;  // phase1 row-quad
  const int vq   = lane & 7;   // phase2 vocab-quad
  const int rp   = lane >> 3;  // phase2 row-pair

  float c_reg = 0.f;           // cell state: tid owns (row=gid*16+(tid>>4), unit=mem*16+(tid&15))
  const size_t BTVo = (size_t)B_ * T_ * V_;
  const int row_base = gid * 16;
  const int vb = mem * 32;

  for (int t = 0; t < T_; ++t) {
    const float* hsrc = hbuf + (size_t)((t + 1) & 1) * (B_ * H_);
    float* hdst = hbuf + (size_t)(t & 1) * (B_ * H_);

    // ---------------- Phase 1: tokens poll (+ t=0 h staging) -------------
    if (t == 0) {
      const unsigned long long* hq =
          (const unsigned long long*)(hsrc + (size_t)row_base * H_);
      unsigned long long v[16];
#pragma unroll
      for (int i = 0; i < 16; ++i)
        v[i] = AT_LOAD((unsigned long long*)&hq[tid + i * 256]);
#pragma unroll
      for (int i = 0; i < 16; ++i) {
        const int idx = tid + i * 256;
        *(unsigned long long*)&sm.hs[idx >> 8][(idx & 255) * 2] = v[i];
      }
    }
    {
      // poll 32 tagged partials per row (2 per thread), reduce to token
      const int prow = tid >> 4, pj = tid & 15;
      const unsigned expect = (unsigned)(t + 1) << 16;   // tag(t-1) = t+1
      const unsigned long long* ap =
          amax + ((size_t)((t + 1) & 1) * B_ + row_base + prow) * 32;
      unsigned long long w1 = AT_LOAD(&ap[pj]);
      unsigned long long w2 = AT_LOAD(&ap[pj + 16]);
      while ((((unsigned)w1 ^ expect) & 0xFFFF0000u) ||
             (((unsigned)w2 ^ expect) & 0xFFFF0000u)) {
        __builtin_amdgcn_s_sleep(1);
        if (((unsigned)w1 ^ expect) & 0xFFFF0000u) w1 = AT_LOAD(&ap[pj]);
        if (((unsigned)w2 ^ expect) & 0xFFFF0000u) w2 = AT_LOAD(&ap[pj + 16]);
      }
      __atomic_signal_fence(__ATOMIC_ACQ_REL);
      float v  = __uint_as_float((unsigned)(w1 >> 32));
      int   ix = (int)((unsigned)w1 & 0xFFFFu);
      const float v2  = __uint_as_float((unsigned)(w2 >> 32));
      const int   ix2 = (int)((unsigned)w2 & 0xFFFFu);
      if (v2 > v || (v2 == v && ix2 < ix)) { v = v2; ix = ix2; }
#pragma unroll
      for (int d = 8; d >= 1; d >>= 1) {
        const float vo = __shfl_xor(v, d, 16);
        const int   io = __shfl_xor(ix, d, 16);
        if (vo > v || (vo == v && io < ix)) { v = vo; ix = io; }
      }
      if (pj == 0) sm.u.p1.tok[prow] = ix;
    }
    __syncthreads();

    // ---------------- Phase 1 GEMM: 16 rows x 64 gate-rows x K512 --------
    {
      float acc[4][4];
#pragma unroll
      for (int a = 0; a < 4; ++a)
#pragma unroll
        for (int b = 0; b < 4; ++b) acc[a][b] = 0.f;
      const int kbase = kc * 128;
      const int uu = mem * 16 + gq;
      const float* wp0 = Whh + (size_t)(uu +    0) * H_ + kbase;
      const float* wp1 = Whh + (size_t)(uu +  512) * H_ + kbase;
      const float* wp2 = Whh + (size_t)(uu + 1024) * H_ + kbase;
      const float* wp3 = Whh + (size_t)(uu + 1536) * H_ + kbase;
#pragma unroll 2
      for (int kk = 0; kk < 128; kk += 4) {
        const float4 w0 = *(const float4*)(wp0 + kk);
        const float4 w1 = *(const float4*)(wp1 + kk);
        const float4 w2 = *(const float4*)(wp2 + kk);
        const float4 w3 = *(const float4*)(wp3 + kk);
#pragma unroll
        for (int ri = 0; ri < 4; ++ri) {
          const float4 h4 = *(const float4*)&sm.hs[rq * 4 + ri][kbase + kk];
          acc[0][ri] = fmaf(w0.x, h4.x, fmaf(w0.y, h4.y, fmaf(w0.z, h4.z, fmaf(w0.w, h4.w, acc[0][ri]))));
          acc[1][ri] = fmaf(w1.x, h4.x, fmaf(w1.y, h4.y, fmaf(w1.z, h4.z, fmaf(w1.w, h4.w, acc[1][ri]))));
          acc[2][ri] = fmaf(w2.x, h4.x, fmaf(w2.y, h4.y, fmaf(w2.z, h4.z, fmaf(w2.w, h4.w, acc[2][ri]))));
          acc[3][ri] = fmaf(w3.x, h4.x, fmaf(w3.y, h4.y, fmaf(w3.z, h4.z, fmaf(w3.w, h4.w, acc[3][ri]))));
        }
      }
#pragma unroll
      for (int gi = 0; gi < 4; ++gi)
        *(float4*)&sm.u.p1.pb1[kc][gq * 4 + gi][rq * 4] =
            make_float4(acc[gi][0], acc[gi][1], acc[gi][2], acc[gi][3]);
    }
    __syncthreads();

    // combine K-partials + base + proj-emb -> gbuf (4 rows per thread)
    {
      const int gl = tid >> 2;
      const int r0 = (tid & 3) * 4;
      const float4 v0 = *(const float4*)&sm.u.p1.pb1[0][gl][r0];
      const float4 v1 = *(const float4*)&sm.u.p1.pb1[1][gl][r0];
      const float4 v2 = *(const float4*)&sm.u.p1.pb1[2][gl][r0];
      const float4 v3 = *(const float4*)&sm.u.p1.pb1[3][gl][r0];
      const float sum[4] = {v0.x + v1.x + v2.x + v3.x, v0.y + v1.y + v2.y + v3.y,
                            v0.z + v1.z + v2.z + v3.z, v0.w + v1.w + v2.w + v3.w};
      const int ul = gl >> 2, gi = gl & 3;
      const int gidx = mem * 16 + ul + gi * 512;
#pragma unroll
      for (int j = 0; j < 4; ++j) {
        const int row = row_base + r0 + j;
        const int tk  = sm.u.p1.tok[r0 + j];
        sm.u.p1.gbuf[r0 + j][ul * 4 + gi] =
            sum[j] + basep[(size_t)row * G4_ + gidx] + proj[(size_t)tk * G4_ + gidx];
      }
    }
    __syncthreads();

    // LSTM epilogue: c in register; h pair-packed 8B bypass stores
    {
      const int rl = tid >> 4, ul = tid & 15;
      const float4 g4 = *(const float4*)&sm.u.p1.gbuf[rl][ul * 4];
      const float ig = 1.f / (1.f + expf(-g4.x));
      const float fg = 1.f / (1.f + expf(-g4.y));
      const float gg = tanhf(g4.z);
      const float og = 1.f / (1.f + expf(-g4.w));
      const float cn = fg * c_reg + ig * gg;
      c_reg = cn;
      const float hn = og * tanhf(cn);
      const int row = row_base + rl, hid = mem * 16 + ul;
      const float hn2 = __shfl_down(hn, 1);
      if ((ul & 1) == 0) {
        const unsigned long long pk =
            (unsigned long long)__float_as_uint(hn) |
            (((unsigned long long)__float_as_uint(hn2)) << 32);
        AT_STORE((unsigned long long*)&hdst[(size_t)row * H_ + hid], pk);
      }
      if (t == T_ - 1) {
        out[BTVo + (size_t)row * H_ + hid] = hn;                    // h_f
        out[BTVo + (size_t)B_ * H_ + (size_t)row * H_ + hid] = cn;  // c_f
      }
    }
    __syncthreads();   // drains vmcnt -> release for hdone flag
    if (tid == 0)
      AT_STORE(&hdone[(((t & 1) * 8 + gid) * 32 + mem) * 16], t + 2);

    // ---------------- Phase 2: stage h(t), logits + argmax ---------------
    if (tid < 32) {
      int* fp = &hdone[(((t & 1) * 8 + gid) * 32 + tid) * 16];
      while (AT_LOAD(fp) != t + 2) __builtin_amdgcn_s_sleep(1);
    }
    __atomic_signal_fence(__ATOMIC_ACQ_REL);
    __syncthreads();
    {
      const unsigned long long* hq =
          (const unsigned long long*)(hdst + (size_t)row_base * H_);
      unsigned long long v[16];
#pragma unroll
      for (int i = 0; i < 16; ++i)
        v[i] = AT_LOAD((unsigned long long*)&hq[tid + i * 256]);
#pragma unroll
      for (int i = 0; i < 16; ++i) {
        const int idx = tid + i * 256;
        *(unsigned long long*)&sm.hs[idx >> 8][(idx & 255) * 2] = v[i];
      }
    }
    __syncthreads();

    // GEMM2: 16 rows x 32 vocab x K512
    {
      float acc2[4][2];
#pragma unroll
      for (int a = 0; a < 4; ++a) { acc2[a][0] = 0.f; acc2[a][1] = 0.f; }
      const int kbase = kc * 128;
      const float* wq[4];
#pragma unroll
      for (int vi = 0; vi < 4; ++vi) {
        const int vv = vb + vq * 4 + vi;
        wq[vi] = Wout + (size_t)(vv < V_ ? vv : 0) * H_ + kbase;
      }
#pragma unroll 2
      for (int kk = 0; kk < 128; kk += 4) {
        const float4 w0 = *(const float4*)(wq[0] + kk);
        const float4 w1 = *(const float4*)(wq[1] + kk);
        const float4 w2 = *(const float4*)(wq[2] + kk);
        const float4 w3 = *(const float4*)(wq[3] + kk);
#pragma unroll
        for (int ri = 0; ri < 2; ++ri) {
          const float4 h4 = *(const float4*)&sm.hs[rp * 2 + ri][kbase + kk];
          acc2[0][ri] = fmaf(w0.x, h4.x, fmaf(w0.y, h4.y, fmaf(w0.z, h4.z, fmaf(w0.w, h4.w, acc2[0][ri]))));
          acc2[1][ri] = fmaf(w1.x, h4.x, fmaf(w1.y, h4.y, fmaf(w1.z, h4.z, fmaf(w1.w, h4.w, acc2[1][ri]))));
          acc2[2][ri] = fmaf(w2.x, h4.x, fmaf(w2.y, h4.y, fmaf(w2.z, h4.z, fmaf(w2.w, h4.w, acc2[2][ri]))));
          acc2[3][ri] = fmaf(w3.x, h4.x, fmaf(w3.y, h4.y, fmaf(w3.z, h4.z, fmaf(w3.w, h4.w, acc2[3][ri]))));
        }
      }
#pragma unroll
      for (int vi = 0; vi < 4; ++vi) {
        sm.u.p2.pb2[kc][vq * 4 + vi][rp * 2 + 0] = acc2[vi][0];
        sm.u.p2.pb2[kc][vq * 4 + vi][rp * 2 + 1] = acc2[vi][1];
      }
    }
    __syncthreads();

    // combine + bias + store logits + lbuf (2 outputs per thread)
    {
      const int vl = tid >> 3;          // 0..31
      const int r0 = (tid & 7) * 2;     // 0..14
      float s0 = sm.u.p2.pb2[0][vl][r0] + sm.u.p2.pb2[1][vl][r0] +
                 sm.u.p2.pb2[2][vl][r0] + sm.u.p2.pb2[3][vl][r0];
      float s1 = sm.u.p2.pb2[0][vl][r0+1] + sm.u.p2.pb2[1][vl][r0+1] +
                 sm.u.p2.pb2[2][vl][r0+1] + sm.u.p2.pb2[3][vl][r0+1];
      const int vv = vb + vl;
      if (vv < V_) {
        const float bz = bout[vv];
        s0 += bz; s1 += bz;
        out[((size_t)(row_base + r0) * T_ + t) * V_ + vv] = s0;
        out[((size_t)(row_base + r0 + 1) * T_ + t) * V_ + vv] = s1;
        sm.u.p2.lbuf[r0][vl] = s0;
        sm.u.p2.lbuf[r0 + 1][vl] = s1;
      } else {
        sm.u.p2.lbuf[r0][vl] = -FLT_MAX;
        sm.u.p2.lbuf[r0 + 1][vl] = -FLT_MAX;
      }
    }
    __syncthreads();

    // per-member argmax partial: 16 rows x 32 vocab, shuffle width 16
    {
      const int r = tid >> 4, j = tid & 15;
      const float v1 = sm.u.p2.lbuf[r][j];
      const float v2 = sm.u.p2.lbuf[r][j + 16];
      float v; int ix;
      if (v2 > v1) { v = v2; ix = j + 16; } else { v = v1; ix = j; }
#pragma unroll
      for (int d = 8; d >= 1; d >>= 1) {
        const float vo = __shfl_xor(v, d, 16);
        const int   io = __shfl_xor(ix, d, 16);
        if (vo > v || (vo == v && io < ix)) { v = vo; ix = io; }
      }
      if (j == 0) {
        const unsigned long long pk =
            (((unsigned long long)__float_as_uint(v)) << 32) |
            ((unsigned)(t + 2) << 16) | (unsigned)(vb + ix);
        AT_STORE(&amax[((size_t)(t & 1) * B_ + row_base + r) * 32 + mem], pk);
      }
    }
    // no barrier: loop back to phase-1 poll of next step
  }
}

// ---------------------------------------------------------------------------
extern "C" void kernel_launch(void* const* d_in, const int* in_sizes, int n_in,
                              void* d_out, int out_size, void* d_ws, size_t ws_size,
                              hipStream_t stream)
{
  const float* ctx   = (const float*)d_in[0];
  const float* emb   = (const float*)d_in[1];
  const float* Wih   = (const float*)d_in[2];
  const float* bih   = (const float*)d_in[3];
  const float* Whh   = (const float*)d_in[4];
  const float* bhh   = (const float*)d_in[5];
  const float* Wout  = (const float*)d_in[6];
  const float* bout  = (const float*)d_in[7];
  const int*   start = (const int*)d_in[8];
  float* out = (float*)d_out;

  // workspace layout (bytes)
  char* ws = (char*)d_ws;
  float* proj  = (float*)(ws + 0);                    // 1000*2048*4 = 8,192,000
  float* basep = (float*)(ws + 8192000);              // 128*2048*4  = 1,048,576
  float* hbuf  = (float*)(ws + 9240576);              // 2*128*512*4 =   524,288
  unsigned long long* amax = (unsigned long long*)(ws + 9764864);  // 2*128*32*8 = 65,536
  int*   hdone = (int*)(ws + 9830400);                // 2*8*32*64B  =    32,768

  hipLaunchKernelGGL(gemm_nt_k512, dim3(32, 2), dim3(256), 0, stream,
                     ctx, B_, Wih, 1024, 0, bih, bhh, basep, G4_);
  hipLaunchKernelGGL(gemm_nt_k512, dim3(32, 16), dim3(256), 0, stream,
                     emb, V_, Wih, 1024, 512, (const float*)nullptr, (const float*)nullptr,
                     proj, G4_);
  hipLaunchKernelGGL(init_kernel, dim3(64), dim3(256), 0, stream,
                     ctx, hbuf, amax, hdone, start);

  void* args[] = {(void*)&Whh, (void*)&Wout, (void*)&bout, (void*)&proj, (void*)&basep,
                  (void*)&hbuf, (void*)&amax, (void*)&hdone, (void*)&out};
  hipLaunchCooperativeKernel(reinterpret_cast<const void*>(decoder_main),
                             dim3(NBLK), dim3(256), args, 0, stream);
}

// Round 6
// 7568.491 us; speedup vs baseline: 3.0935x; 1.2126x over previous
//
#include <hip/hip_runtime.h>
#include <float.h>
#include <math.h>

#define B_    128
#define H_    512
#define V_    1000
#define T_    256
#define G4_   2048
#define NBLK  256     // cooperative launch limit: 1 block/CU (512 failed to launch in r3/r4)

#define AT_LOAD(p)    __hip_atomic_load((p), __ATOMIC_RELAXED, __HIP_MEMORY_SCOPE_AGENT)
#define AT_STORE(p,v) __hip_atomic_store((p), (v), __ATOMIC_RELAXED, __HIP_MEMORY_SCOPE_AGENT)

// ---------------------------------------------------------------------------
// Precompute GEMM:  C[M][N] = A[M][0:512] * Bm[N][koff:koff+512]^T (+bias1+bias2)
// ---------------------------------------------------------------------------
__global__ __launch_bounds__(256) void gemm_nt_k512(
    const float* __restrict__ A, int M,
    const float* __restrict__ Bm, int ldb, int koff,
    const float* __restrict__ bias1, const float* __restrict__ bias2,
    float* __restrict__ C, int ldc)
{
  __shared__ float As[16][68];
  __shared__ float Bs[16][68];
  const int tid = threadIdx.x;
  const int m0 = blockIdx.y * 64, n0 = blockIdx.x * 64;
  const int tm = tid & 15, tn = tid >> 4;
  const int lm = tid & 63, kq = tid >> 6;
  float acc[4][4] = {};
  for (int k0 = 0; k0 < 512; k0 += 16) {
    float4 av = make_float4(0.f, 0.f, 0.f, 0.f);
    if (m0 + lm < M) av = *(const float4*)(A + (size_t)(m0 + lm) * 512 + k0 + kq * 4);
    float4 bv = *(const float4*)(Bm + (size_t)(n0 + lm) * ldb + koff + k0 + kq * 4);
    __syncthreads();
    As[kq*4+0][lm] = av.x; As[kq*4+1][lm] = av.y; As[kq*4+2][lm] = av.z; As[kq*4+3][lm] = av.w;
    Bs[kq*4+0][lm] = bv.x; Bs[kq*4+1][lm] = bv.y; Bs[kq*4+2][lm] = bv.z; Bs[kq*4+3][lm] = bv.w;
    __syncthreads();
#pragma unroll
    for (int kk = 0; kk < 16; ++kk) {
      const float4 a = *(const float4*)&As[kk][tm * 4];
      const float4 b = *(const float4*)&Bs[kk][tn * 4];
      const float aa[4] = {a.x, a.y, a.z, a.w};
      const float bb[4] = {b.x, b.y, b.z, b.w};
#pragma unroll
      for (int i = 0; i < 4; ++i)
#pragma unroll
        for (int j = 0; j < 4; ++j)
          acc[i][j] = fmaf(aa[i], bb[j], acc[i][j]);
    }
  }
#pragma unroll
  for (int i = 0; i < 4; ++i) {
    const int m = m0 + tm * 4 + i;
    if (m < M) {
#pragma unroll
      for (int j = 0; j < 4; ++j) {
        const int n = n0 + tn * 4 + j;
        float v = acc[i][j];
        if (bias1) v += bias1[n];
        if (bias2) v += bias2[n];
        C[(size_t)m * ldc + n] = v;
      }
    }
  }
}

// ---------------------------------------------------------------------------
// amax word: [val:f32 bits in high 32][tag:16][token:16]; tag(t) = t+2.
// ---------------------------------------------------------------------------
__global__ __launch_bounds__(256) void init_kernel(
    const float* __restrict__ ctx, float* __restrict__ hbuf,
    unsigned long long* __restrict__ amax,
    int* __restrict__ hdone, const int* __restrict__ start_id)
{
  const int i = blockIdx.x * blockDim.x + threadIdx.x;
  // h(-1) = context into slot 1
  ((float4*)(hbuf + B_ * H_))[i] = ((const float4*)ctx)[i];
  if (i < B_ * 32) {
    const int m = i & 31;
    const unsigned long long w = (m == 0)
        ? ((((unsigned long long)__float_as_uint(FLT_MAX)) << 32) |
           (1u << 16) | (unsigned)(*start_id))
        : ((((unsigned long long)__float_as_uint(-FLT_MAX)) << 32) | (1u << 16));
    amax[(size_t)B_ * 32 + i] = w;   // parity-1 slot, tag(-1)=1
  }
  if (i < 2 * 8 * 32) hdone[i * 16] = 0;
}

// ---------------------------------------------------------------------------
// Persistent cooperative decoder, 1024 threads/block (16 waves = 4/SIMD for
// latency hiding; r5's 256-thread blocks ran 1 wave/SIMD -> 86% stall).
// 8 groups x 32 blocks; group g owns rows [16g,16g+16). Zero barriers:
// tagged-dataflow sync (r5-verified).
// Phase 1: lane owns (gate-row, batch-row) full-K -> no K-combine.
// Phase 2: lane owns (vocab, row, K-half) -> one shfl_xor combine.
// ---------------------------------------------------------------------------
__global__ __launch_bounds__(1024) void decoder_main(
    const float* __restrict__ Whh,
    const float* __restrict__ Wout,
    const float* __restrict__ bout,
    const float* __restrict__ proj,
    const float* __restrict__ basep,
    float* __restrict__ hbuf,
    unsigned long long* __restrict__ amax,
    int* __restrict__ hdone,
    float* __restrict__ out)
{
  __shared__ struct alignas(16) SM {
    float hs[16][516];          // h tile; persists phase2(t) -> phase1(t+1)
    union {
      struct { float gbuf[16][65]; int tok[16]; } p1;  // stride 65: free writes, <=4-way b128 read
      struct { float lbuf[16][33]; } p2;
    } u;
  } sm;

  const int tid  = threadIdx.x;
  const int bid  = blockIdx.x;
  const int gid  = bid >> 5;     // group: rows [16g, 16g+16)
  const int mem  = bid & 31;     // member: units [16*mem,+16) / vocab [32*mem,+32)
  const int lane = tid & 63;
  const int w    = tid >> 6;     // wave 0..15
  const int row_base = gid * 16;
  const int vb   = mem * 32;

  // phase-1 lane constants: quad q1 of wave w owns gate-line 4w+q1; lane&15 = batch row
  const int q1 = (lane >> 4) & 3;
  const int r1 = lane & 15;
  const int gl4 = (w << 2) | q1;            // 0..63
  const int u1 = gl4 & 15, g1 = gl4 >> 4;   // unit-in-slice, gate
  const int gidx = mem * 16 + u1 + g1 * 512;
  const float* wp1 = Whh + (size_t)gidx * H_;

  // phase-2 lane constants
  const int q2 = lane >> 5;                 // vocab sub 0..1
  const int kh = (lane >> 4) & 1;           // K half
  const int r2 = lane & 15;                 // batch row
  const int v2 = vb + w * 2 + q2;
  const float* wp2 = Wout + (size_t)(v2 < V_ ? v2 : 0) * H_ + kh * 256;

  float c_reg = 0.f;   // tid<256 owns cell (row=row_base+(tid>>4), unit=mem*16+(tid&15))
  const size_t BTVo = (size_t)B_ * T_ * V_;

  for (int t = 0; t < T_; ++t) {
    float* hdst = hbuf + (size_t)(t & 1) * (B_ * H_);

    // ---------------- Phase 1: t=0 staging + token poll ------------------
    if (t == 0) {
      const float* hsrc = hbuf + (size_t)B_ * H_;   // slot 1 = context
      const unsigned long long* hq =
          (const unsigned long long*)(hsrc + (size_t)row_base * H_);
      unsigned long long v[4];
#pragma unroll
      for (int i = 0; i < 4; ++i)
        v[i] = AT_LOAD((unsigned long long*)&hq[tid + i * 1024]);
#pragma unroll
      for (int i = 0; i < 4; ++i) {
        const int idx = tid + i * 1024;
        *(unsigned long long*)&sm.hs[idx >> 8][(idx & 255) * 2] = v[i];
      }
    }
    if (tid < 512) {
      // 16 rows x 32 tagged partials; one word per thread, shfl-reduce width 32
      const int prow = tid >> 5, pj = tid & 31;
      const unsigned expect = (unsigned)(t + 1) << 16;   // tag(t-1) = t+1
      const unsigned long long* ap =
          amax + ((size_t)((t + 1) & 1) * B_ + row_base + prow) * 32;
      unsigned long long wv = AT_LOAD(&ap[pj]);
      while (((unsigned)wv ^ expect) & 0xFFFF0000u) {
        __builtin_amdgcn_s_sleep(1);
        wv = AT_LOAD(&ap[pj]);
      }
      __atomic_signal_fence(__ATOMIC_ACQ_REL);
      float v  = __uint_as_float((unsigned)(wv >> 32));
      int   ix = (int)((unsigned)wv & 0xFFFFu);
#pragma unroll
      for (int d = 16; d >= 1; d >>= 1) {
        const float vo = __shfl_xor(v, d, 32);
        const int   io = __shfl_xor(ix, d, 32);
        if (vo > v || (vo == v && io < ix)) { v = vo; ix = io; }
      }
      if (pj == 0) sm.u.p1.tok[prow] = ix;
    }
    __syncthreads();

    // ---------------- Phase 1 GEMM: lane = (gate-line, row), full K ------
    {
      const int rowg = row_base + r1;
      const float bp = basep[(size_t)rowg * G4_ + gidx];
      const int tk = sm.u.p1.tok[r1];
      const float pj = proj[(size_t)tk * G4_ + gidx];
      float a0 = 0.f, a1 = 0.f, a2 = 0.f, a3 = 0.f;
#pragma unroll 4
      for (int k = 0; k < 512; k += 16) {
        const float4 w0 = *(const float4*)(wp1 + k);
        const float4 w1 = *(const float4*)(wp1 + k + 4);
        const float4 w2 = *(const float4*)(wp1 + k + 8);
        const float4 w3 = *(const float4*)(wp1 + k + 12);
        const float4 h0 = *(const float4*)&sm.hs[r1][k];
        const float4 h1 = *(const float4*)&sm.hs[r1][k + 4];
        const float4 h2 = *(const float4*)&sm.hs[r1][k + 8];
        const float4 h3 = *(const float4*)&sm.hs[r1][k + 12];
        a0 = fmaf(w0.x, h0.x, fmaf(w0.y, h0.y, fmaf(w0.z, h0.z, fmaf(w0.w, h0.w, a0))));
        a1 = fmaf(w1.x, h1.x, fmaf(w1.y, h1.y, fmaf(w1.z, h1.z, fmaf(w1.w, h1.w, a1))));
        a2 = fmaf(w2.x, h2.x, fmaf(w2.y, h2.y, fmaf(w2.z, h2.z, fmaf(w2.w, h2.w, a2))));
        a3 = fmaf(w3.x, h3.x, fmaf(w3.y, h3.y, fmaf(w3.z, h3.z, fmaf(w3.w, h3.w, a3))));
      }
      sm.u.p1.gbuf[r1][u1 * 4 + g1] = (a0 + a1) + (a2 + a3) + bp + pj;
    }
    __syncthreads();

    // ---------------- LSTM epilogue (tid<256): c in register -------------
    if (tid < 256) {
      const int rl = tid >> 4, ul = tid & 15;
      const float4 g4 = *(const float4*)&sm.u.p1.gbuf[rl][ul * 4];
      const float ig = 1.f / (1.f + expf(-g4.x));
      const float fg = 1.f / (1.f + expf(-g4.y));
      const float gg = tanhf(g4.z);
      const float og = 1.f / (1.f + expf(-g4.w));
      const float cn = fg * c_reg + ig * gg;
      c_reg = cn;
      const float hn = og * tanhf(cn);
      const int row = row_base + rl, hid = mem * 16 + ul;
      const float hn2 = __shfl_down(hn, 1);
      if ((ul & 1) == 0) {
        const unsigned long long pk =
            (unsigned long long)__float_as_uint(hn) |
            (((unsigned long long)__float_as_uint(hn2)) << 32);
        AT_STORE((unsigned long long*)&hdst[(size_t)row * H_ + hid], pk);
      }
      if (t == T_ - 1) {
        out[BTVo + (size_t)row * H_ + hid] = hn;                    // h_f
        out[BTVo + (size_t)B_ * H_ + (size_t)row * H_ + hid] = cn;  // c_f
      }
    }
    __syncthreads();   // drains vmcnt -> release for hdone flag
    if (tid == 0)
      AT_STORE(&hdone[(((t & 1) * 8 + gid) * 32 + mem) * 16], t + 2);

    // ---------------- Phase 2: stage h(t), logits + argmax ---------------
    if (tid < 32) {
      int* fp = &hdone[(((t & 1) * 8 + gid) * 32 + tid) * 16];
      while (AT_LOAD(fp) != t + 2) __builtin_amdgcn_s_sleep(1);
    }
    __atomic_signal_fence(__ATOMIC_ACQ_REL);
    __syncthreads();
    {
      const unsigned long long* hq =
          (const unsigned long long*)(hdst + (size_t)row_base * H_);
      unsigned long long v[4];
#pragma unroll
      for (int i = 0; i < 4; ++i)
        v[i] = AT_LOAD((unsigned long long*)&hq[tid + i * 1024]);
#pragma unroll
      for (int i = 0; i < 4; ++i) {
        const int idx = tid + i * 1024;
        *(unsigned long long*)&sm.hs[idx >> 8][(idx & 255) * 2] = v[i];
      }
    }
    __syncthreads();

    // GEMM2: lane = (vocab, row, K-half); shfl_xor(16) combines halves
    {
      const float bz = (v2 < V_) ? bout[v2] : 0.f;
      float a0 = 0.f, a1 = 0.f, a2 = 0.f, a3 = 0.f;
      const int kb = kh * 256;
#pragma unroll 4
      for (int k = 0; k < 256; k += 16) {
        const float4 w0 = *(const float4*)(wp2 + k);
        const float4 w1 = *(const float4*)(wp2 + k + 4);
        const float4 w2 = *(const float4*)(wp2 + k + 8);
        const float4 w3 = *(const float4*)(wp2 + k + 12);
        const float4 h0 = *(const float4*)&sm.hs[r2][kb + k];
        const float4 h1 = *(const float4*)&sm.hs[r2][kb + k + 4];
        const float4 h2 = *(const float4*)&sm.hs[r2][kb + k + 8];
        const float4 h3 = *(const float4*)&sm.hs[r2][kb + k + 12];
        a0 = fmaf(w0.x, h0.x, fmaf(w0.y, h0.y, fmaf(w0.z, h0.z, fmaf(w0.w, h0.w, a0))));
        a1 = fmaf(w1.x, h1.x, fmaf(w1.y, h1.y, fmaf(w1.z, h1.z, fmaf(w1.w, h1.w, a1))));
        a2 = fmaf(w2.x, h2.x, fmaf(w2.y, h2.y, fmaf(w2.z, h2.z, fmaf(w2.w, h2.w, a2))));
        a3 = fmaf(w3.x, h3.x, fmaf(w3.y, h3.y, fmaf(w3.z, h3.z, fmaf(w3.w, h3.w, a3))));
      }
      float s = (a0 + a1) + (a2 + a3);
      s += __shfl_xor(s, 16);                 // combine K halves
      if (kh == 0) {
        if (v2 < V_) {
          s += bz;
          out[((size_t)(row_base + r2) * T_ + t) * V_ + v2] = s;
          sm.u.p2.lbuf[r2][w * 2 + q2] = s;
        } else {
          sm.u.p2.lbuf[r2][w * 2 + q2] = -FLT_MAX;
        }
      }
    }
    __syncthreads();

    // per-member argmax partial: 16 rows x 32 vocab, shfl-reduce width 32
    if (tid < 512) {
      const int r = tid >> 5, j = tid & 31;
      float v = sm.u.p2.lbuf[r][j];
      int ix = j;
#pragma unroll
      for (int d = 16; d >= 1; d >>= 1) {
        const float vo = __shfl_xor(v, d, 32);
        const int   io = __shfl_xor(ix, d, 32);
        if (vo > v || (vo == v && io < ix)) { v = vo; ix = io; }
      }
      if (j == 0) {
        const unsigned long long pk =
            (((unsigned long long)__float_as_uint(v)) << 32) |
            ((unsigned)(t + 2) << 16) | (unsigned)(vb + ix);
        AT_STORE(&amax[((size_t)(t & 1) * B_ + row_base + r) * 32 + mem], pk);
      }
    }
    // no barrier: loop back to next step's poll
  }
}

// ---------------------------------------------------------------------------
extern "C" void kernel_launch(void* const* d_in, const int* in_sizes, int n_in,
                              void* d_out, int out_size, void* d_ws, size_t ws_size,
                              hipStream_t stream)
{
  const float* ctx   = (const float*)d_in[0];
  const float* emb   = (const float*)d_in[1];
  const float* Wih   = (const float*)d_in[2];
  const float* bih   = (const float*)d_in[3];
  const float* Whh   = (const float*)d_in[4];
  const float* bhh   = (const float*)d_in[5];
  const float* Wout  = (const float*)d_in[6];
  const float* bout  = (const float*)d_in[7];
  const int*   start = (const int*)d_in[8];
  float* out = (float*)d_out;

  // workspace layout (bytes)
  char* ws = (char*)d_ws;
  float* proj  = (float*)(ws + 0);                    // 1000*2048*4 = 8,192,000
  float* basep = (float*)(ws + 8192000);              // 128*2048*4  = 1,048,576
  float* hbuf  = (float*)(ws + 9240576);              // 2*128*512*4 =   524,288
  unsigned long long* amax = (unsigned long long*)(ws + 9764864);  // 2*128*32*8 = 65,536
  int*   hdone = (int*)(ws + 9830400);                // 2*8*32*64B  =    32,768

  hipLaunchKernelGGL(gemm_nt_k512, dim3(32, 2), dim3(256), 0, stream,
                     ctx, B_, Wih, 1024, 0, bih, bhh, basep, G4_);
  hipLaunchKernelGGL(gemm_nt_k512, dim3(32, 16), dim3(256), 0, stream,
                     emb, V_, Wih, 1024, 512, (const float*)nullptr, (const float*)nullptr,
                     proj, G4_);
  hipLaunchKernelGGL(init_kernel, dim3(64), dim3(256), 0, stream,
                     ctx, hbuf, amax, hdone, start);

  void* args[] = {(void*)&Whh, (void*)&Wout, (void*)&bout, (void*)&proj, (void*)&basep,
                  (void*)&hbuf, (void*)&amax, (void*)&hdone, (void*)&out};
  hipLaunchCooperativeKernel(reinterpret_cast<const void*>(decoder_main),
                             dim3(NBLK), dim3(1024), args, 0, stream);
}